// Round 6
// baseline (1532.048 us; speedup 1.0000x reference)
//
#include <hip/hip_runtime.h>

typedef unsigned int uint;
typedef unsigned short ushort;

#define NN 100000
#define EE 3200000
#define DD 128
#define NCH ((NN + 1023) / 1024)  // 98 scan chunks
#define TM 32                     // rows per k_linv block

// ---- all scratch static: zero dependence on ws_size ----
__device__ __attribute__((aligned(256))) int g_deg[NN];
__device__ __attribute__((aligned(256))) int g_cursor[NN];
__device__ __attribute__((aligned(256))) int g_offs[NN + 1];
__device__ __attribute__((aligned(256))) int g_csum[NCH + 1];
__device__ __attribute__((aligned(256))) int g_flag[2];  // [0]=edge is64, [1]=float is fp32
__device__ __attribute__((aligned(256))) int g_csr[EE];
__device__ __attribute__((aligned(256))) float g_embf[(size_t)NN * DD];
__device__ __attribute__((aligned(256))) float g_aggf[(size_t)NN * DD];
__device__ __attribute__((aligned(256))) float g_h[(size_t)NN * DD];
__device__ __attribute__((aligned(256))) float g_wf[4][DD * DD];  // Wl0,Wr0,Wl1,Wr1
__device__ __attribute__((aligned(256))) float g_biasf[2][DD];    // b0,b1

__device__ __forceinline__ float b2f(ushort s) { return __uint_as_float(((uint)s) << 16); }

// ---- dtype detection -----------------------------------------------------
__global__ void k_detect_ei(const int* __restrict__ ei) {
  __shared__ int any;
  if (threadIdx.x == 0) any = 0;
  __syncthreads();
  int v = 0;
  for (int i = threadIdx.x; i < 2048; i += 256) v |= ei[2 * i + 1];
  if (v) atomicOr(&any, 1);
  __syncthreads();
  if (threadIdx.x == 0) g_flag[0] = (any == 0) ? 1 : 0;  // 1 => int64
}

// bf16 Gaussian elements have exponent in [0x40,0x7F]; fp32 low-mantissa
// words are uniform => out-of-band quickly.
__global__ void k_detect_f(const ushort* __restrict__ u) {
  __shared__ int bad;
  if (threadIdx.x == 0) bad = 0;
  __syncthreads();
  int b = 0;
  for (int i = threadIdx.x; i < 2048; i += 256) {
    int e = (u[2 * i] >> 7) & 0xff;
    if (e < 0x40 || e > 0x7f) b = 1;
  }
  if (b) atomicOr(&bad, 1);
  __syncthreads();
  if (threadIdx.x == 0) g_flag[1] = bad;  // 1 => fp32
}

// ---- canonicalize float tensors to fp32 scratch -------------------------
__global__ void k_cvtf(const void* __restrict__ src, float* __restrict__ dst, int n) {
  int i = (blockIdx.x * blockDim.x + threadIdx.x) * 4;
  if (i >= n) return;
  if (g_flag[1]) {
    *(float4*)(dst + i) = *(const float4*)((const float*)src + i);
  } else {
    ushort4 s = *(const ushort4*)((const ushort*)src + i);
    float4 f;
    f.x = b2f(s.x); f.y = b2f(s.y); f.z = b2f(s.z); f.w = b2f(s.w);
    *(float4*)(dst + i) = f;
  }
}

__global__ void k_cvtb(const void* __restrict__ src, float* __restrict__ dst, int n) {
  int i = blockIdx.x * blockDim.x + threadIdx.x;
  if (i >= n) return;
  dst[i] = g_flag[1] ? ((const float*)src)[i] : b2f(((const ushort*)src)[i]);
}

__device__ __forceinline__ int ld_src(const int* __restrict__ ei, int is64, int e) {
  int v = is64 ? ei[2 * e] : ei[e];
  return ((uint)v < (uint)NN) ? v : 0;
}
__device__ __forceinline__ int ld_dst(const int* __restrict__ ei, int is64, int e) {
  int v = is64 ? ei[2 * (EE + e)] : ei[EE + e];
  return ((uint)v < (uint)NN) ? v : 0;
}

// ---------------- CSR build ----------------

__global__ void k_zero() {
  int i = blockIdx.x * blockDim.x + threadIdx.x;
  if (i < NN) g_deg[i] = 0;
}

__global__ void k_deg(const int* __restrict__ ei) {
  int is64 = g_flag[0];
  int e = blockIdx.x * blockDim.x + threadIdx.x;
  if (e < EE) atomicAdd(&g_deg[ld_dst(ei, is64, e)], 1);
}

__global__ void k_scan_a() {
  __shared__ int sd[256];
  int t = threadIdx.x;
  int base = blockIdx.x * 1024 + t * 4;
  int s = 0;
#pragma unroll
  for (int k = 0; k < 4; k++) {
    int i = base + k;
    if (i < NN) s += g_deg[i];
  }
  sd[t] = s;
  __syncthreads();
  for (int off = 128; off > 0; off >>= 1) {
    if (t < off) sd[t] += sd[t + off];
    __syncthreads();
  }
  if (t == 0) g_csum[blockIdx.x] = sd[0];
}

__global__ void k_scan_b() {
  if (threadIdx.x == 0 && blockIdx.x == 0) {
    int run = 0;
    for (int i = 0; i < NCH; i++) {
      int v = g_csum[i];
      g_csum[i] = run;
      run += v;
    }
    g_offs[NN] = run;  // == EE
  }
}

__global__ void k_scan_c() {
  __shared__ int sd[256];
  int t = threadIdx.x;
  int base = blockIdx.x * 1024 + t * 4;
  int v[4];
  int s = 0;
#pragma unroll
  for (int k = 0; k < 4; k++) {
    int i = base + k;
    v[k] = (i < NN) ? g_deg[i] : 0;
    s += v[k];
  }
  sd[t] = s;
  __syncthreads();
  for (int off = 1; off < 256; off <<= 1) {
    int x = (t >= off) ? sd[t - off] : 0;
    __syncthreads();
    sd[t] += x;
    __syncthreads();
  }
  int excl = sd[t] - s + g_csum[blockIdx.x];
#pragma unroll
  for (int k = 0; k < 4; k++) {
    int i = base + k;
    if (i < NN) {
      g_offs[i] = excl;
      g_cursor[i] = excl;
      excl += v[k];
    }
  }
}

__global__ void k_scatter(const int* __restrict__ ei) {
  int is64 = g_flag[0];
  int e = blockIdx.x * blockDim.x + threadIdx.x;
  if (e < EE) {
    int p = atomicAdd(&g_cursor[ld_dst(ei, is64, e)], 1);
    if ((uint)p < (uint)EE) g_csr[p] = ld_src(ei, is64, e);
  }
}

// ---------------- mean aggregation, fp32 (one wave per node) --------------
__global__ void k_aggf(const float* __restrict__ x, float* __restrict__ agg) {
  int lane = threadIdx.x & 63;
  int node = (blockIdx.x * blockDim.x + threadIdx.x) >> 6;
  int beg = g_offs[node], end = g_offs[node + 1];
  float a0 = 0.f, a1 = 0.f;
  int col = lane * 2;
  for (int c = beg; c < end; c += 64) {
    int cnt = end - c;
    if (cnt > 64) cnt = 64;
    int my = g_csr[c + (lane < cnt ? lane : cnt - 1)];
    if ((uint)my >= (uint)NN) my = 0;
    int cnt4 = cnt & ~3;
    int j = 0;
    for (; j < cnt4; j += 4) {
      int s0 = __shfl(my, j), s1 = __shfl(my, j + 1);
      int s2 = __shfl(my, j + 2), s3 = __shfl(my, j + 3);
      float2 r0 = *(const float2*)(x + (size_t)s0 * DD + col);
      float2 r1 = *(const float2*)(x + (size_t)s1 * DD + col);
      float2 r2 = *(const float2*)(x + (size_t)s2 * DD + col);
      float2 r3 = *(const float2*)(x + (size_t)s3 * DD + col);
      a0 += r0.x + r1.x + r2.x + r3.x;
      a1 += r0.y + r1.y + r2.y + r3.y;
    }
    for (; j < cnt; ++j) {
      int s = __shfl(my, j);
      float2 r = *(const float2*)(x + (size_t)s * DD + col);
      a0 += r.x;
      a1 += r.y;
    }
  }
  int deg = end - beg;
  float inv = deg > 0 ? 1.0f / (float)deg : 0.f;
  float2 o;
  o.x = a0 * inv;
  o.y = a1 * inv;
  *(float2*)(agg + (size_t)node * DD + col) = o;
}

// ---------------- fp32 VALU linear: out = act(A1@Wl^T + b + A2@Wr^T) ------
// Block: 256 threads = 4 waves, TM=32 rows. Wave w handles rows w*8..w*8+7;
// lane l handles cols 2l, 2l+1. LDS holds the 32x128 A-tiles (reads are
// wave-uniform -> broadcast).
// MODE 0: bias+ReLU -> fp32.  MODE 1: bias + row-L2-normalize -> fp32 OUTPUT.

template <int MODE>
__global__ __launch_bounds__(256) void k_linv(const float* __restrict__ A1,
                                              const float* __restrict__ A2,
                                              const float* __restrict__ Wl,
                                              const float* __restrict__ Wr,
                                              const float* __restrict__ bias,
                                              float* outp) {
  __shared__ float sA1[TM][DD], sA2[TM][DD];
  int t = threadIdx.x;
  int row0 = blockIdx.x * TM;
  {
    int r = t >> 3, c0 = (t & 7) * 16;
    const float4* p1 = (const float4*)(A1 + (size_t)(row0 + r) * DD + c0);
    const float4* p2 = (const float4*)(A2 + (size_t)(row0 + r) * DD + c0);
    float4* q1 = (float4*)&sA1[r][c0];
    float4* q2 = (float4*)&sA2[r][c0];
#pragma unroll
    for (int i = 0; i < 4; i++) {
      q1[i] = p1[i];
      q2[i] = p2[i];
    }
  }
  __syncthreads();
  int l = t & 63, w = t >> 6;
  int c = l * 2;
  int r0 = w * 8;
  float acc[8][2];
  float bv0 = bias[c], bv1 = bias[c + 1];
#pragma unroll
  for (int r = 0; r < 8; r++) {
    acc[r][0] = bv0;
    acc[r][1] = bv1;
  }
  const float* wl0 = Wl + (size_t)c * DD;
  const float* wl1 = Wl + (size_t)(c + 1) * DD;
  const float* wr0 = Wr + (size_t)c * DD;
  const float* wr1 = Wr + (size_t)(c + 1) * DD;
  for (int k = 0; k < DD; k += 4) {
    float4 L0 = *(const float4*)(wl0 + k);
    float4 L1 = *(const float4*)(wl1 + k);
    float4 R0 = *(const float4*)(wr0 + k);
    float4 R1 = *(const float4*)(wr1 + k);
#pragma unroll
    for (int r = 0; r < 8; r++) {
      float4 a = *(const float4*)&sA1[r0 + r][k];
      float4 b = *(const float4*)&sA2[r0 + r][k];
      acc[r][0] += a.x * L0.x + a.y * L0.y + a.z * L0.z + a.w * L0.w +
                   b.x * R0.x + b.y * R0.y + b.z * R0.z + b.w * R0.w;
      acc[r][1] += a.x * L1.x + a.y * L1.y + a.z * L1.z + a.w * L1.w +
                   b.x * R1.x + b.y * R1.y + b.z * R1.z + b.w * R1.w;
    }
  }
  if (MODE == 0) {
#pragma unroll
    for (int r = 0; r < 8; r++) {
      float2 o;
      o.x = acc[r][0] > 0.f ? acc[r][0] : 0.f;
      o.y = acc[r][1] > 0.f ? acc[r][1] : 0.f;
      *(float2*)(outp + (size_t)(row0 + r0 + r) * DD + c) = o;
    }
  } else {
#pragma unroll
    for (int r = 0; r < 8; r++) {
      float p = acc[r][0] * acc[r][0] + acc[r][1] * acc[r][1];
#pragma unroll
      for (int m = 1; m < 64; m <<= 1) p += __shfl_xor(p, m);
      float inv = (p > 0.f) ? 1.0f / fmaxf(sqrtf(p), 1e-12f) : 0.f;
      float2 o;
      o.x = acc[r][0] * inv;
      o.y = acc[r][1] * inv;
      // fp32 OUTPUT — the reference's output dtype (this was the r4/r5 bug)
      *(float2*)(outp + (size_t)(row0 + r0 + r) * DD + c) = o;
    }
  }
}

// ---------------- launch ----------------

extern "C" void kernel_launch(void* const* d_in, const int* in_sizes, int n_in,
                              void* d_out, int out_size, void* d_ws, size_t ws_size,
                              hipStream_t stream) {
  const int* ei = (const int*)d_in[0];
  (void)in_sizes; (void)n_in; (void)out_size; (void)d_ws; (void)ws_size;

  float* wf;    hipGetSymbolAddress((void**)&wf, HIP_SYMBOL(g_wf));
  float* wl0 = wf;
  float* wr0 = wf + DD * DD;
  float* wl1 = wf + 2 * DD * DD;
  float* wr1 = wf + 3 * DD * DD;
  float* bf;    hipGetSymbolAddress((void**)&bf, HIP_SYMBOL(g_biasf));
  float* b0 = bf;
  float* b1 = bf + DD;
  float* embf;  hipGetSymbolAddress((void**)&embf, HIP_SYMBOL(g_embf));
  float* aggf;  hipGetSymbolAddress((void**)&aggf, HIP_SYMBOL(g_aggf));
  float* hf;    hipGetSymbolAddress((void**)&hf, HIP_SYMBOL(g_h));

  const int eb = (EE + 255) / 256;
  k_detect_ei<<<1, 256, 0, stream>>>(ei);
  k_detect_f<<<1, 256, 0, stream>>>((const ushort*)d_in[1]);

  k_cvtf<<<(NN * DD / 4 + 255) / 256, 256, 0, stream>>>(d_in[1], embf, NN * DD);
  k_cvtf<<<(DD * DD / 4 + 255) / 256, 256, 0, stream>>>(d_in[2], wl0, DD * DD);
  k_cvtf<<<(DD * DD / 4 + 255) / 256, 256, 0, stream>>>(d_in[4], wr0, DD * DD);
  k_cvtf<<<(DD * DD / 4 + 255) / 256, 256, 0, stream>>>(d_in[5], wl1, DD * DD);
  k_cvtf<<<(DD * DD / 4 + 255) / 256, 256, 0, stream>>>(d_in[7], wr1, DD * DD);
  k_cvtb<<<1, 128, 0, stream>>>(d_in[3], b0, DD);
  k_cvtb<<<1, 128, 0, stream>>>(d_in[6], b1, DD);

  k_zero<<<(NN + 255) / 256, 256, 0, stream>>>();
  k_deg<<<eb, 256, 0, stream>>>(ei);
  k_scan_a<<<NCH, 256, 0, stream>>>();
  k_scan_b<<<1, 64, 0, stream>>>();
  k_scan_c<<<NCH, 256, 0, stream>>>();
  k_scatter<<<eb, 256, 0, stream>>>(ei);

  k_aggf<<<NN / 4, 256, 0, stream>>>(embf, aggf);
  k_linv<0><<<NN / TM, 256, 0, stream>>>(aggf, embf, wl0, wr0, b0, hf);
  k_aggf<<<NN / 4, 256, 0, stream>>>(hf, aggf);
  k_linv<1><<<NN / TM, 256, 0, stream>>>(aggf, hf, wl1, wr1, b1, (float*)d_out);
}

// Round 7
// 975.615 us; speedup vs baseline: 1.5703x; 1.5703x over previous
//
#include <hip/hip_runtime.h>

typedef unsigned int uint;
typedef unsigned short ushort;
typedef __bf16 v8b __attribute__((ext_vector_type(8)));
typedef float v4f __attribute__((ext_vector_type(4)));

#define NN 100000
#define EE 3200000
#define DD 128
#define NCH ((NN + 1023) / 1024)  // 98 scan chunks

// ---- all scratch static: zero dependence on ws_size ----
__device__ __attribute__((aligned(256))) int g_deg[NN];
__device__ __attribute__((aligned(256))) int g_cursor[NN];
__device__ __attribute__((aligned(256))) int g_offs[NN + 1];
__device__ __attribute__((aligned(256))) int g_csum[NCH + 1];
__device__ __attribute__((aligned(256))) int g_flag[2];  // [0]=edge is64, [1]=float is fp32
__device__ __attribute__((aligned(256))) int g_csr[EE];
// bf16 hi/lo split representations (hi also serves as the gather array)
__device__ __attribute__((aligned(256))) ushort g_emb_h[(size_t)NN * DD];
__device__ __attribute__((aligned(256))) ushort g_emb_l[(size_t)NN * DD];
__device__ __attribute__((aligned(256))) ushort g_agg_h[(size_t)NN * DD];
__device__ __attribute__((aligned(256))) ushort g_agg_l[(size_t)NN * DD];
__device__ __attribute__((aligned(256))) ushort g_hh[(size_t)NN * DD];
__device__ __attribute__((aligned(256))) ushort g_hl[(size_t)NN * DD];
__device__ __attribute__((aligned(256))) ushort g_w_h[4][DD * DD];  // Wl0,Wr0,Wl1,Wr1
__device__ __attribute__((aligned(256))) ushort g_w_l[4][DD * DD];
__device__ __attribute__((aligned(256))) float g_biasf[2][DD];  // b0,b1

__device__ __forceinline__ float blo(uint u) { return __uint_as_float(u << 16); }
__device__ __forceinline__ float bhi(uint u) { return __uint_as_float(u & 0xffff0000u); }
__device__ __forceinline__ ushort f2b(float f) {
  uint u = __float_as_uint(f);
  u += 0x7fffu + ((u >> 16) & 1u);  // RNE
  return (ushort)(u >> 16);
}
__device__ __forceinline__ float b2f(ushort s) { return __uint_as_float(((uint)s) << 16); }

// ---- dtype detection -----------------------------------------------------
__global__ void k_detect_ei(const int* __restrict__ ei) {
  __shared__ int any;
  if (threadIdx.x == 0) any = 0;
  __syncthreads();
  int v = 0;
  for (int i = threadIdx.x; i < 2048; i += 256) v |= ei[2 * i + 1];
  if (v) atomicOr(&any, 1);
  __syncthreads();
  if (threadIdx.x == 0) g_flag[0] = (any == 0) ? 1 : 0;  // 1 => int64
}

__global__ void k_detect_f(const ushort* __restrict__ u) {
  __shared__ int bad;
  if (threadIdx.x == 0) bad = 0;
  __syncthreads();
  int b = 0;
  for (int i = threadIdx.x; i < 2048; i += 256) {
    int e = (u[2 * i] >> 7) & 0xff;
    if (e < 0x40 || e > 0x7f) b = 1;
  }
  if (b) atomicOr(&bad, 1);
  __syncthreads();
  if (threadIdx.x == 0) g_flag[1] = bad;  // 1 => fp32
}

// ---- split fp32 (or bf16) tensor into bf16 hi + lo residual -------------
__global__ void k_split(const void* __restrict__ src, ushort* __restrict__ dh,
                        ushort* __restrict__ dl, int n) {
  int i = (blockIdx.x * blockDim.x + threadIdx.x) * 4;
  if (i >= n) return;
  float f[4];
  if (g_flag[1]) {
    float4 v = *(const float4*)((const float*)src + i);
    f[0] = v.x; f[1] = v.y; f[2] = v.z; f[3] = v.w;
  } else {
    ushort4 s = *(const ushort4*)((const ushort*)src + i);
    f[0] = b2f(s.x); f[1] = b2f(s.y); f[2] = b2f(s.z); f[3] = b2f(s.w);
  }
  ushort4 h, l;
  ushort* hp = &h.x;
  ushort* lp = &l.x;
#pragma unroll
  for (int k = 0; k < 4; k++) {
    ushort hi = f2b(f[k]);
    hp[k] = hi;
    lp[k] = f2b(f[k] - b2f(hi));
  }
  *(ushort4*)(dh + i) = h;
  *(ushort4*)(dl + i) = l;
}

__global__ void k_cvtb(const void* __restrict__ src, float* __restrict__ dst, int n) {
  int i = blockIdx.x * blockDim.x + threadIdx.x;
  if (i >= n) return;
  dst[i] = g_flag[1] ? ((const float*)src)[i] : b2f(((const ushort*)src)[i]);
}

__device__ __forceinline__ int ld_src(const int* __restrict__ ei, int is64, int e) {
  int v = is64 ? ei[2 * e] : ei[e];
  return ((uint)v < (uint)NN) ? v : 0;
}
__device__ __forceinline__ int ld_dst(const int* __restrict__ ei, int is64, int e) {
  int v = is64 ? ei[2 * (EE + e)] : ei[EE + e];
  return ((uint)v < (uint)NN) ? v : 0;
}

// ---------------- CSR build ----------------

__global__ void k_zero() {
  int i = blockIdx.x * blockDim.x + threadIdx.x;
  if (i < NN) g_deg[i] = 0;
}

__global__ void k_deg(const int* __restrict__ ei) {
  int is64 = g_flag[0];
  int e = blockIdx.x * blockDim.x + threadIdx.x;
  if (e < EE) atomicAdd(&g_deg[ld_dst(ei, is64, e)], 1);
}

__global__ void k_scan_a() {
  __shared__ int sd[256];
  int t = threadIdx.x;
  int base = blockIdx.x * 1024 + t * 4;
  int s = 0;
#pragma unroll
  for (int k = 0; k < 4; k++) {
    int i = base + k;
    if (i < NN) s += g_deg[i];
  }
  sd[t] = s;
  __syncthreads();
  for (int off = 128; off > 0; off >>= 1) {
    if (t < off) sd[t] += sd[t + off];
    __syncthreads();
  }
  if (t == 0) g_csum[blockIdx.x] = sd[0];
}

__global__ void k_scan_b() {
  if (threadIdx.x == 0 && blockIdx.x == 0) {
    int run = 0;
    for (int i = 0; i < NCH; i++) {
      int v = g_csum[i];
      g_csum[i] = run;
      run += v;
    }
    g_offs[NN] = run;  // == EE
  }
}

__global__ void k_scan_c() {
  __shared__ int sd[256];
  int t = threadIdx.x;
  int base = blockIdx.x * 1024 + t * 4;
  int v[4];
  int s = 0;
#pragma unroll
  for (int k = 0; k < 4; k++) {
    int i = base + k;
    v[k] = (i < NN) ? g_deg[i] : 0;
    s += v[k];
  }
  sd[t] = s;
  __syncthreads();
  for (int off = 1; off < 256; off <<= 1) {
    int x = (t >= off) ? sd[t - off] : 0;
    __syncthreads();
    sd[t] += x;
    __syncthreads();
  }
  int excl = sd[t] - s + g_csum[blockIdx.x];
#pragma unroll
  for (int k = 0; k < 4; k++) {
    int i = base + k;
    if (i < NN) {
      g_offs[i] = excl;
      g_cursor[i] = excl;
      excl += v[k];
    }
  }
}

__global__ void k_scatter(const int* __restrict__ ei) {
  int is64 = g_flag[0];
  int e = blockIdx.x * blockDim.x + threadIdx.x;
  if (e < EE) {
    int p = atomicAdd(&g_cursor[ld_dst(ei, is64, e)], 1);
    if ((uint)p < (uint)EE) g_csr[p] = ld_src(ei, is64, e);
  }
}

// ------- mean aggregation: bf16 gather, fp32 accum, hi/lo bf16 out -------
// One wave per node; lane holds cols 2l,2l+1 (one uint = 2 bf16).
__global__ void k_agg(const ushort* __restrict__ x) {
  int lane = threadIdx.x & 63;
  int node = (blockIdx.x * blockDim.x + threadIdx.x) >> 6;
  int beg = g_offs[node], end = g_offs[node + 1];
  float a0 = 0.f, a1 = 0.f;
  int col = lane * 2;
  for (int c = beg; c < end; c += 64) {
    int cnt = end - c;
    if (cnt > 64) cnt = 64;
    int my = g_csr[c + (lane < cnt ? lane : cnt - 1)];
    if ((uint)my >= (uint)NN) my = 0;
    int cnt4 = cnt & ~3;
    int j = 0;
    for (; j < cnt4; j += 4) {
      int s0 = __shfl(my, j), s1 = __shfl(my, j + 1);
      int s2 = __shfl(my, j + 2), s3 = __shfl(my, j + 3);
      uint r0 = *(const uint*)(x + (size_t)s0 * DD + col);
      uint r1 = *(const uint*)(x + (size_t)s1 * DD + col);
      uint r2 = *(const uint*)(x + (size_t)s2 * DD + col);
      uint r3 = *(const uint*)(x + (size_t)s3 * DD + col);
      a0 += blo(r0) + blo(r1) + blo(r2) + blo(r3);
      a1 += bhi(r0) + bhi(r1) + bhi(r2) + bhi(r3);
    }
    for (; j < cnt; ++j) {
      int s = __shfl(my, j);
      uint r = *(const uint*)(x + (size_t)s * DD + col);
      a0 += blo(r);
      a1 += bhi(r);
    }
  }
  int deg = end - beg;
  float inv = deg > 0 ? 1.0f / (float)deg : 0.f;
  a0 *= inv;
  a1 *= inv;
  ushort h0 = f2b(a0), h1 = f2b(a1);
  ushort l0 = f2b(a0 - b2f(h0)), l1 = f2b(a1 - b2f(h1));
  size_t o = (size_t)node * DD + col;
  *(uint*)(g_agg_h + o) = (uint)h0 | ((uint)h1 << 16);
  *(uint*)(g_agg_l + o) = (uint)l0 | ((uint)l1 << 16);
}

// ------- MFMA linear, bf16x3: out = act(A1@Wl^T + b + A2@Wr^T) -----------
// (ah+al)(bh+bl) ~= ah*bh + ah*bl + al*bh  (error ~2^-16 rel, fp32 accum)
// One wave = 16 rows x 128 cols, mfma_f32_16x16x32_bf16.
// A frag: row=lane&15, k=(lane>>4)*8+j.  B frag: W row n=lane&15, same k.
// C/D: col=lane&15, row=(lane>>4)*4+reg.   (layouts verified: r4===r5 bitwise)
// MODE 0: bias+ReLU -> h hi/lo bf16.  MODE 1: bias+L2-normalize -> fp32 out.

template <int MODE>
__global__ __launch_bounds__(128) void k_lin(
    const ushort* __restrict__ A1h, const ushort* __restrict__ A1l,
    const ushort* __restrict__ A2h, const ushort* __restrict__ A2l,
    const ushort* __restrict__ Wlh, const ushort* __restrict__ Wll,
    const ushort* __restrict__ Wrh, const ushort* __restrict__ Wrl,
    const float* __restrict__ bias, void* out0, ushort* __restrict__ outlo) {
  int lane = threadIdx.x & 63;
  int wid = threadIdx.x >> 6;
  int m = lane & 15, q = lane >> 4;
  int row0 = (blockIdx.x * 2 + wid) * 16;
  size_t aoff = (size_t)(row0 + m) * DD + q * 8;
  v8b a1h[4], a1l[4], a2h[4], a2l[4];
#pragma unroll
  for (int ks = 0; ks < 4; ks++) {
    a1h[ks] = *(const v8b*)(A1h + aoff + ks * 32);
    a1l[ks] = *(const v8b*)(A1l + aoff + ks * 32);
    a2h[ks] = *(const v8b*)(A2h + aoff + ks * 32);
    a2l[ks] = *(const v8b*)(A2l + aoff + ks * 32);
  }
  v4f acc[8];
#pragma unroll
  for (int nt = 0; nt < 8; nt++) {
    v4f c = {0.f, 0.f, 0.f, 0.f};
    size_t boff = (size_t)(nt * 16 + m) * DD + q * 8;
#pragma unroll
    for (int ks = 0; ks < 4; ks++) {
      v8b blh = *(const v8b*)(Wlh + boff + ks * 32);
      v8b bll = *(const v8b*)(Wll + boff + ks * 32);
      v8b brh = *(const v8b*)(Wrh + boff + ks * 32);
      v8b brl = *(const v8b*)(Wrl + boff + ks * 32);
      c = __builtin_amdgcn_mfma_f32_16x16x32_bf16(a1h[ks], blh, c, 0, 0, 0);
      c = __builtin_amdgcn_mfma_f32_16x16x32_bf16(a1h[ks], bll, c, 0, 0, 0);
      c = __builtin_amdgcn_mfma_f32_16x16x32_bf16(a1l[ks], blh, c, 0, 0, 0);
      c = __builtin_amdgcn_mfma_f32_16x16x32_bf16(a2h[ks], brh, c, 0, 0, 0);
      c = __builtin_amdgcn_mfma_f32_16x16x32_bf16(a2h[ks], brl, c, 0, 0, 0);
      c = __builtin_amdgcn_mfma_f32_16x16x32_bf16(a2l[ks], brh, c, 0, 0, 0);
    }
    float bv = bias[nt * 16 + m];
#pragma unroll
    for (int r = 0; r < 4; r++) c[r] += bv;
    acc[nt] = c;
  }
  if (MODE == 0) {
    ushort* oh = (ushort*)out0;
#pragma unroll
    for (int nt = 0; nt < 8; nt++) {
#pragma unroll
      for (int r = 0; r < 4; r++) {
        float v = acc[nt][r];
        v = v > 0.f ? v : 0.f;
        ushort hi = f2b(v);
        ushort lo = f2b(v - b2f(hi));
        size_t o = (size_t)(row0 + q * 4 + r) * DD + nt * 16 + m;
        oh[o] = hi;
        outlo[o] = lo;
      }
    }
  } else {
    float* of = (float*)out0;
#pragma unroll
    for (int r = 0; r < 4; r++) {
      float p = 0.f;
#pragma unroll
      for (int nt = 0; nt < 8; nt++) p += acc[nt][r] * acc[nt][r];
      p += __shfl_xor(p, 1);
      p += __shfl_xor(p, 2);
      p += __shfl_xor(p, 4);
      p += __shfl_xor(p, 8);
      float inv = (p > 0.f) ? 1.0f / fmaxf(sqrtf(p), 1e-12f) : 0.f;
#pragma unroll
      for (int nt = 0; nt < 8; nt++)
        of[(size_t)(row0 + q * 4 + r) * DD + nt * 16 + m] = acc[nt][r] * inv;
    }
  }
}

// ---------------- launch ----------------

extern "C" void kernel_launch(void* const* d_in, const int* in_sizes, int n_in,
                              void* d_out, int out_size, void* d_ws, size_t ws_size,
                              hipStream_t stream) {
  const int* ei = (const int*)d_in[0];
  (void)in_sizes; (void)n_in; (void)out_size; (void)d_ws; (void)ws_size;

  ushort* wh;  hipGetSymbolAddress((void**)&wh, HIP_SYMBOL(g_w_h));
  ushort* wl;  hipGetSymbolAddress((void**)&wl, HIP_SYMBOL(g_w_l));
  ushort* wl0h = wh, *wr0h = wh + DD * DD, *wl1h = wh + 2 * DD * DD, *wr1h = wh + 3 * DD * DD;
  ushort* wl0l = wl, *wr0l = wl + DD * DD, *wl1l = wl + 2 * DD * DD, *wr1l = wl + 3 * DD * DD;
  float* bf;   hipGetSymbolAddress((void**)&bf, HIP_SYMBOL(g_biasf));
  float* b0 = bf, *b1 = bf + DD;
  ushort* eh;  hipGetSymbolAddress((void**)&eh, HIP_SYMBOL(g_emb_h));
  ushort* el;  hipGetSymbolAddress((void**)&el, HIP_SYMBOL(g_emb_l));
  ushort* ah;  hipGetSymbolAddress((void**)&ah, HIP_SYMBOL(g_agg_h));
  ushort* al;  hipGetSymbolAddress((void**)&al, HIP_SYMBOL(g_agg_l));
  ushort* hh;  hipGetSymbolAddress((void**)&hh, HIP_SYMBOL(g_hh));
  ushort* hl;  hipGetSymbolAddress((void**)&hl, HIP_SYMBOL(g_hl));

  const int eb = (EE + 255) / 256;
  k_detect_ei<<<1, 256, 0, stream>>>(ei);
  k_detect_f<<<1, 256, 0, stream>>>((const ushort*)d_in[1]);

  k_split<<<(NN * DD / 4 + 255) / 256, 256, 0, stream>>>(d_in[1], eh, el, NN * DD);
  k_split<<<(DD * DD / 4 + 255) / 256, 256, 0, stream>>>(d_in[2], wl0h, wl0l, DD * DD);
  k_split<<<(DD * DD / 4 + 255) / 256, 256, 0, stream>>>(d_in[4], wr0h, wr0l, DD * DD);
  k_split<<<(DD * DD / 4 + 255) / 256, 256, 0, stream>>>(d_in[5], wl1h, wl1l, DD * DD);
  k_split<<<(DD * DD / 4 + 255) / 256, 256, 0, stream>>>(d_in[7], wr1h, wr1l, DD * DD);
  k_cvtb<<<1, 128, 0, stream>>>(d_in[3], b0, DD);
  k_cvtb<<<1, 128, 0, stream>>>(d_in[6], b1, DD);

  k_zero<<<(NN + 255) / 256, 256, 0, stream>>>();
  k_deg<<<eb, 256, 0, stream>>>(ei);
  k_scan_a<<<NCH, 256, 0, stream>>>();
  k_scan_b<<<1, 64, 0, stream>>>();
  k_scan_c<<<NCH, 256, 0, stream>>>();
  k_scatter<<<eb, 256, 0, stream>>>(ei);

  k_agg<<<NN / 4, 256, 0, stream>>>(eh);
  k_lin<0><<<NN / 32, 128, 0, stream>>>(ah, al, eh, el, wl0h, wl0l, wr0h, wr0l, b0, hh, hl);
  k_agg<<<NN / 4, 256, 0, stream>>>(hh);
  k_lin<1><<<NN / 32, 128, 0, stream>>>(ah, al, hh, hl, wl1h, wl1l, wr1h, wr1l, b1, d_out, nullptr);
}

// Round 8
// 855.530 us; speedup vs baseline: 1.7908x; 1.1404x over previous
//
#include <hip/hip_runtime.h>

typedef unsigned int uint;
typedef unsigned short ushort;
typedef __bf16 v8b __attribute__((ext_vector_type(8)));
typedef float v4f __attribute__((ext_vector_type(4)));

#define NN 100000
#define EE 3200000
#define DD 128
#define NCH ((NN + 1023) / 1024)  // 98 scan chunks
#define NSLICE 8
#define SLICE_SZ (NN / NSLICE)  // 12500, exact

// ---- all scratch static: zero dependence on ws_size ----
__device__ __attribute__((aligned(256))) int g_deg[NN];
__device__ __attribute__((aligned(256))) int g_cursor[NN];
__device__ __attribute__((aligned(256))) int g_offs[NN + 1];
__device__ __attribute__((aligned(256))) int g_csum[NCH + 1];
__device__ __attribute__((aligned(256))) int g_flag[2];  // [0]=edge is64, [1]=float is fp32
__device__ __attribute__((aligned(256))) int g_csr[EE];
// bf16 hi/lo split representations (hi also serves as the gather array)
__device__ __attribute__((aligned(256))) ushort g_emb_h[(size_t)NN * DD];
__device__ __attribute__((aligned(256))) ushort g_emb_l[(size_t)NN * DD];
__device__ __attribute__((aligned(256))) ushort g_agg_h[(size_t)NN * DD];
__device__ __attribute__((aligned(256))) ushort g_agg_l[(size_t)NN * DD];
__device__ __attribute__((aligned(256))) ushort g_hh[(size_t)NN * DD];
__device__ __attribute__((aligned(256))) ushort g_hl[(size_t)NN * DD];
__device__ __attribute__((aligned(256))) ushort g_w_h[4][DD * DD];  // Wl0,Wr0,Wl1,Wr1
__device__ __attribute__((aligned(256))) ushort g_w_l[4][DD * DD];
__device__ __attribute__((aligned(256))) float g_biasf[2][DD];  // b0,b1

__device__ __forceinline__ float blo(uint u) { return __uint_as_float(u << 16); }
__device__ __forceinline__ float bhi(uint u) { return __uint_as_float(u & 0xffff0000u); }
__device__ __forceinline__ ushort f2b(float f) {
  uint u = __float_as_uint(f);
  u += 0x7fffu + ((u >> 16) & 1u);  // RNE
  return (ushort)(u >> 16);
}
__device__ __forceinline__ float b2f(ushort s) { return __uint_as_float(((uint)s) << 16); }

// ---- dtype detection -----------------------------------------------------
__global__ void k_detect_ei(const int* __restrict__ ei) {
  __shared__ int any;
  if (threadIdx.x == 0) any = 0;
  __syncthreads();
  int v = 0;
  for (int i = threadIdx.x; i < 2048; i += 256) v |= ei[2 * i + 1];
  if (v) atomicOr(&any, 1);
  __syncthreads();
  if (threadIdx.x == 0) g_flag[0] = (any == 0) ? 1 : 0;  // 1 => int64
}

__global__ void k_detect_f(const ushort* __restrict__ u) {
  __shared__ int bad;
  if (threadIdx.x == 0) bad = 0;
  __syncthreads();
  int b = 0;
  for (int i = threadIdx.x; i < 2048; i += 256) {
    int e = (u[2 * i] >> 7) & 0xff;
    if (e < 0x40 || e > 0x7f) b = 1;
  }
  if (b) atomicOr(&bad, 1);
  __syncthreads();
  if (threadIdx.x == 0) g_flag[1] = bad;  // 1 => fp32
}

// ---- split fp32 (or bf16) tensor into bf16 hi + lo residual -------------
__global__ void k_split(const void* __restrict__ src, ushort* __restrict__ dh,
                        ushort* __restrict__ dl, int n) {
  int i = (blockIdx.x * blockDim.x + threadIdx.x) * 4;
  if (i >= n) return;
  float f[4];
  if (g_flag[1]) {
    float4 v = *(const float4*)((const float*)src + i);
    f[0] = v.x; f[1] = v.y; f[2] = v.z; f[3] = v.w;
  } else {
    ushort4 s = *(const ushort4*)((const ushort*)src + i);
    f[0] = b2f(s.x); f[1] = b2f(s.y); f[2] = b2f(s.z); f[3] = b2f(s.w);
  }
  ushort4 h, l;
  ushort* hp = &h.x;
  ushort* lp = &l.x;
#pragma unroll
  for (int k = 0; k < 4; k++) {
    ushort hi = f2b(f[k]);
    hp[k] = hi;
    lp[k] = f2b(f[k] - b2f(hi));
  }
  *(ushort4*)(dh + i) = h;
  *(ushort4*)(dl + i) = l;
}

__global__ void k_cvtb(const void* __restrict__ src, float* __restrict__ dst, int n) {
  int i = blockIdx.x * blockDim.x + threadIdx.x;
  if (i >= n) return;
  dst[i] = g_flag[1] ? ((const float*)src)[i] : b2f(((const ushort*)src)[i]);
}

__device__ __forceinline__ int ld_src(const int* __restrict__ ei, int is64, int e) {
  int v = is64 ? ei[2 * e] : ei[e];
  return ((uint)v < (uint)NN) ? v : 0;
}
__device__ __forceinline__ int ld_dst(const int* __restrict__ ei, int is64, int e) {
  int v = is64 ? ei[2 * (EE + e)] : ei[EE + e];
  return ((uint)v < (uint)NN) ? v : 0;
}

// ---------------- CSR build ----------------

__global__ void k_zero() {
  int i = blockIdx.x * blockDim.x + threadIdx.x;
  if (i < NN) g_deg[i] = 0;
}

// 4 edges/thread, coalesced, independent atomic chains for MLP
__global__ void k_deg(const int* __restrict__ ei) {
  int is64 = g_flag[0];
  int base = blockIdx.x * 1024 + threadIdx.x;
#pragma unroll
  for (int k = 0; k < 4; k++) {
    int e = base + k * 256;
    if (e < EE) atomicAdd(&g_deg[ld_dst(ei, is64, e)], 1);
  }
}

__global__ void k_scan_a() {
  __shared__ int sd[256];
  int t = threadIdx.x;
  int base = blockIdx.x * 1024 + t * 4;
  int s = 0;
#pragma unroll
  for (int k = 0; k < 4; k++) {
    int i = base + k;
    if (i < NN) s += g_deg[i];
  }
  sd[t] = s;
  __syncthreads();
  for (int off = 128; off > 0; off >>= 1) {
    if (t < off) sd[t] += sd[t + off];
    __syncthreads();
  }
  if (t == 0) g_csum[blockIdx.x] = sd[0];
}

__global__ void k_scan_b() {
  if (threadIdx.x == 0 && blockIdx.x == 0) {
    int run = 0;
    for (int i = 0; i < NCH; i++) {
      int v = g_csum[i];
      g_csum[i] = run;
      run += v;
    }
    g_offs[NN] = run;  // == EE
  }
}

__global__ void k_scan_c() {
  __shared__ int sd[256];
  int t = threadIdx.x;
  int base = blockIdx.x * 1024 + t * 4;
  int v[4];
  int s = 0;
#pragma unroll
  for (int k = 0; k < 4; k++) {
    int i = base + k;
    v[k] = (i < NN) ? g_deg[i] : 0;
    s += v[k];
  }
  sd[t] = s;
  __syncthreads();
  for (int off = 1; off < 256; off <<= 1) {
    int x = (t >= off) ? sd[t - off] : 0;
    __syncthreads();
    sd[t] += x;
    __syncthreads();
  }
  int excl = sd[t] - s + g_csum[blockIdx.x];
#pragma unroll
  for (int k = 0; k < 4; k++) {
    int i = base + k;
    if (i < NN) {
      g_offs[i] = excl;
      g_cursor[i] = excl;
      excl += v[k];
    }
  }
}

// dst-sliced scatter: slice = blockIdx&7 (heuristic %8 -> XCD). csr is
// dst-ordered, so each 1.6 MB csr slice is written by exactly one slice
// of blocks -> lines accumulate in one XCD L2, write back once (kills the
// 194 MB random-64B writeback storm seen in r7 counters).
__global__ void k_scatter(const int* __restrict__ ei) {
  int is64 = g_flag[0];
  int slice = blockIdx.x & (NSLICE - 1);
  int lo = slice * SLICE_SZ, hi = lo + SLICE_SZ;
  int base = (blockIdx.x >> 3) * 512 + threadIdx.x;
#pragma unroll
  for (int k = 0; k < 2; k++) {
    int e = base + k * 256;
    if (e < EE) {
      int d = ld_dst(ei, is64, e);
      if (d >= lo && d < hi) {
        int p = atomicAdd(&g_cursor[d], 1);
        if ((uint)p < (uint)EE) g_csr[p] = ld_src(ei, is64, e);
      }
    }
  }
}

// ------- mean aggregation: bf16 gather, fp32 accum, hi/lo bf16 out -------
// One wave per node; lane holds cols 2l,2l+1 (one uint = 2 bf16).
__global__ void k_agg(const ushort* __restrict__ x) {
  int lane = threadIdx.x & 63;
  int node = (blockIdx.x * blockDim.x + threadIdx.x) >> 6;
  int beg = g_offs[node], end = g_offs[node + 1];
  float a0 = 0.f, a1 = 0.f;
  int col = lane * 2;
  for (int c = beg; c < end; c += 64) {
    int cnt = end - c;
    if (cnt > 64) cnt = 64;
    int my = g_csr[c + (lane < cnt ? lane : cnt - 1)];
    if ((uint)my >= (uint)NN) my = 0;
    int cnt4 = cnt & ~3;
    int j = 0;
    for (; j < cnt4; j += 4) {
      int s0 = __shfl(my, j), s1 = __shfl(my, j + 1);
      int s2 = __shfl(my, j + 2), s3 = __shfl(my, j + 3);
      uint r0 = *(const uint*)(x + (size_t)s0 * DD + col);
      uint r1 = *(const uint*)(x + (size_t)s1 * DD + col);
      uint r2 = *(const uint*)(x + (size_t)s2 * DD + col);
      uint r3 = *(const uint*)(x + (size_t)s3 * DD + col);
      a0 += blo(r0) + blo(r1) + blo(r2) + blo(r3);
      a1 += bhi(r0) + bhi(r1) + bhi(r2) + bhi(r3);
    }
    for (; j < cnt; ++j) {
      int s = __shfl(my, j);
      uint r = *(const uint*)(x + (size_t)s * DD + col);
      a0 += blo(r);
      a1 += bhi(r);
    }
  }
  int deg = end - beg;
  float inv = deg > 0 ? 1.0f / (float)deg : 0.f;
  a0 *= inv;
  a1 *= inv;
  ushort h0 = f2b(a0), h1 = f2b(a1);
  ushort l0 = f2b(a0 - b2f(h0)), l1 = f2b(a1 - b2f(h1));
  size_t o = (size_t)node * DD + col;
  *(uint*)(g_agg_h + o) = (uint)h0 | ((uint)h1 << 16);
  *(uint*)(g_agg_l + o) = (uint)l0 | ((uint)l1 << 16);
}

// ------- MFMA linear, bf16x3: out = act(A1@Wl^T + b + A2@Wr^T) -----------
// (ah+al)(bh+bl) ~= ah*bh + ah*bl + al*bh  (error ~2^-16 rel, fp32 accum)
// One wave = 16 rows x 128 cols, mfma_f32_16x16x32_bf16.
// A frag: row=lane&15, k=(lane>>4)*8+j.  B frag: W row n=lane&15, same k.
// C/D: col=lane&15, row=(lane>>4)*4+reg.   (layouts verified: r4===r5 bitwise)
// MODE 0: bias+ReLU -> h hi/lo bf16.  MODE 1: bias+L2-normalize -> fp32 out.

template <int MODE>
__global__ __launch_bounds__(128) void k_lin(
    const ushort* __restrict__ A1h, const ushort* __restrict__ A1l,
    const ushort* __restrict__ A2h, const ushort* __restrict__ A2l,
    const ushort* __restrict__ Wlh, const ushort* __restrict__ Wll,
    const ushort* __restrict__ Wrh, const ushort* __restrict__ Wrl,
    const float* __restrict__ bias, void* out0, ushort* __restrict__ outlo) {
  int lane = threadIdx.x & 63;
  int wid = threadIdx.x >> 6;
  int m = lane & 15, q = lane >> 4;
  int row0 = (blockIdx.x * 2 + wid) * 16;
  size_t aoff = (size_t)(row0 + m) * DD + q * 8;
  v8b a1h[4], a1l[4], a2h[4], a2l[4];
#pragma unroll
  for (int ks = 0; ks < 4; ks++) {
    a1h[ks] = *(const v8b*)(A1h + aoff + ks * 32);
    a1l[ks] = *(const v8b*)(A1l + aoff + ks * 32);
    a2h[ks] = *(const v8b*)(A2h + aoff + ks * 32);
    a2l[ks] = *(const v8b*)(A2l + aoff + ks * 32);
  }
  v4f acc[8];
#pragma unroll
  for (int nt = 0; nt < 8; nt++) {
    v4f c = {0.f, 0.f, 0.f, 0.f};
    size_t boff = (size_t)(nt * 16 + m) * DD + q * 8;
#pragma unroll
    for (int ks = 0; ks < 4; ks++) {
      v8b blh = *(const v8b*)(Wlh + boff + ks * 32);
      v8b bll = *(const v8b*)(Wll + boff + ks * 32);
      v8b brh = *(const v8b*)(Wrh + boff + ks * 32);
      v8b brl = *(const v8b*)(Wrl + boff + ks * 32);
      c = __builtin_amdgcn_mfma_f32_16x16x32_bf16(a1h[ks], blh, c, 0, 0, 0);
      c = __builtin_amdgcn_mfma_f32_16x16x32_bf16(a1h[ks], bll, c, 0, 0, 0);
      c = __builtin_amdgcn_mfma_f32_16x16x32_bf16(a1l[ks], blh, c, 0, 0, 0);
      c = __builtin_amdgcn_mfma_f32_16x16x32_bf16(a2h[ks], brh, c, 0, 0, 0);
      c = __builtin_amdgcn_mfma_f32_16x16x32_bf16(a2h[ks], brl, c, 0, 0, 0);
      c = __builtin_amdgcn_mfma_f32_16x16x32_bf16(a2l[ks], brh, c, 0, 0, 0);
    }
    float bv = bias[nt * 16 + m];
#pragma unroll
    for (int r = 0; r < 4; r++) c[r] += bv;
    acc[nt] = c;
  }
  if (MODE == 0) {
    ushort* oh = (ushort*)out0;
#pragma unroll
    for (int nt = 0; nt < 8; nt++) {
#pragma unroll
      for (int r = 0; r < 4; r++) {
        float v = acc[nt][r];
        v = v > 0.f ? v : 0.f;
        ushort hi = f2b(v);
        ushort lo = f2b(v - b2f(hi));
        size_t o = (size_t)(row0 + q * 4 + r) * DD + nt * 16 + m;
        oh[o] = hi;
        outlo[o] = lo;
      }
    }
  } else {
    float* of = (float*)out0;
#pragma unroll
    for (int r = 0; r < 4; r++) {
      float p = 0.f;
#pragma unroll
      for (int nt = 0; nt < 8; nt++) p += acc[nt][r] * acc[nt][r];
      p += __shfl_xor(p, 1);
      p += __shfl_xor(p, 2);
      p += __shfl_xor(p, 4);
      p += __shfl_xor(p, 8);
      float inv = (p > 0.f) ? 1.0f / fmaxf(sqrtf(p), 1e-12f) : 0.f;
#pragma unroll
      for (int nt = 0; nt < 8; nt++)
        of[(size_t)(row0 + q * 4 + r) * DD + nt * 16 + m] = acc[nt][r] * inv;
    }
  }
}

// ---------------- launch ----------------

extern "C" void kernel_launch(void* const* d_in, const int* in_sizes, int n_in,
                              void* d_out, int out_size, void* d_ws, size_t ws_size,
                              hipStream_t stream) {
  const int* ei = (const int*)d_in[0];
  (void)in_sizes; (void)n_in; (void)out_size; (void)d_ws; (void)ws_size;

  ushort* wh;  hipGetSymbolAddress((void**)&wh, HIP_SYMBOL(g_w_h));
  ushort* wl;  hipGetSymbolAddress((void**)&wl, HIP_SYMBOL(g_w_l));
  ushort* wl0h = wh, *wr0h = wh + DD * DD, *wl1h = wh + 2 * DD * DD, *wr1h = wh + 3 * DD * DD;
  ushort* wl0l = wl, *wr0l = wl + DD * DD, *wl1l = wl + 2 * DD * DD, *wr1l = wl + 3 * DD * DD;
  float* bf;   hipGetSymbolAddress((void**)&bf, HIP_SYMBOL(g_biasf));
  float* b0 = bf, *b1 = bf + DD;
  ushort* eh;  hipGetSymbolAddress((void**)&eh, HIP_SYMBOL(g_emb_h));
  ushort* el;  hipGetSymbolAddress((void**)&el, HIP_SYMBOL(g_emb_l));
  ushort* ah;  hipGetSymbolAddress((void**)&ah, HIP_SYMBOL(g_agg_h));
  ushort* al;  hipGetSymbolAddress((void**)&al, HIP_SYMBOL(g_agg_l));
  ushort* hh;  hipGetSymbolAddress((void**)&hh, HIP_SYMBOL(g_hh));
  ushort* hl;  hipGetSymbolAddress((void**)&hl, HIP_SYMBOL(g_hl));

  k_detect_ei<<<1, 256, 0, stream>>>(ei);
  k_detect_f<<<1, 256, 0, stream>>>((const ushort*)d_in[1]);

  k_split<<<(NN * DD / 4 + 255) / 256, 256, 0, stream>>>(d_in[1], eh, el, NN * DD);
  k_split<<<(DD * DD / 4 + 255) / 256, 256, 0, stream>>>(d_in[2], wl0h, wl0l, DD * DD);
  k_split<<<(DD * DD / 4 + 255) / 256, 256, 0, stream>>>(d_in[4], wr0h, wr0l, DD * DD);
  k_split<<<(DD * DD / 4 + 255) / 256, 256, 0, stream>>>(d_in[5], wl1h, wl1l, DD * DD);
  k_split<<<(DD * DD / 4 + 255) / 256, 256, 0, stream>>>(d_in[7], wr1h, wr1l, DD * DD);
  k_cvtb<<<1, 128, 0, stream>>>(d_in[3], b0, DD);
  k_cvtb<<<1, 128, 0, stream>>>(d_in[6], b1, DD);

  k_zero<<<(NN + 255) / 256, 256, 0, stream>>>();
  k_deg<<<(EE + 1023) / 1024, 256, 0, stream>>>(ei);
  k_scan_a<<<NCH, 256, 0, stream>>>();
  k_scan_b<<<1, 64, 0, stream>>>();
  k_scan_c<<<NCH, 256, 0, stream>>>();
  k_scatter<<<NSLICE * ((EE + 511) / 512), 256, 0, stream>>>(ei);

  k_agg<<<NN / 4, 256, 0, stream>>>(eh);
  k_lin<0><<<NN / 32, 128, 0, stream>>>(ah, al, eh, el, wl0h, wl0l, wr0h, wr0l, b0, hh, hl);
  k_agg<<<NN / 4, 256, 0, stream>>>(hh);
  k_lin<1><<<NN / 32, 128, 0, stream>>>(ah, al, hh, hl, wl1h, wl1l, wr1h, wr1l, b1, d_out, nullptr);
}